// Round 3
// baseline (14276.358 us; speedup 1.0000x reference)
//
#include <hip/hip_runtime.h>
#include <hip/hip_bf16.h>
#include <stdint.h>
#include <math.h>

#define BATCH 256
#define SEQ   256
#define EMB   1024
#define HID   1024
#define NCLASS 32000
#define KTOT  2048   // EMB + HID

typedef __attribute__((ext_vector_type(8))) short bf16x8;   // 8 bf16 (4 VGPRs)
typedef __attribute__((ext_vector_type(4))) float f32x4;    // MFMA accumulator

// ---------- scalar helpers ----------
__device__ __forceinline__ unsigned short f2b(float f) {
  union { float f; unsigned u; } v; v.f = f;
  unsigned r = v.u + 0x7FFFu + ((v.u >> 16) & 1u);   // round-to-nearest-even
  return (unsigned short)(r >> 16);
}
__device__ __forceinline__ float b2f(unsigned short s) {
  union { unsigned u; float f; } v; v.u = ((unsigned)s) << 16;
  return v.f;
}
__device__ __forceinline__ void load_lds16(const void* g, void* l) {
  __builtin_amdgcn_global_load_lds(
      (const __attribute__((address_space(1))) unsigned int*)g,
      (__attribute__((address_space(3))) unsigned int*)l, 16, 0, 0);
}
__device__ __forceinline__ float tanh_fast(float x) {
  // 1 - 2/(e^{2x}+1): saturates to +-1, no NaN at large |x|
  return 1.f - 2.f / (__expf(2.f * x) + 1.f);
}

// ---------- embedding lookup + bf16 cast:  Xt[t*B+b][k] = bf16(C[X[b][t]][k]) ----------
__global__ void embed_kernel(const int* __restrict__ X, const float* __restrict__ C,
                             unsigned short* __restrict__ Xt) {
  int n = blockIdx.x;             // n = t*BATCH + b
  int t = n >> 8, b = n & 255;
  int tok = X[(size_t)b * SEQ + t];
  float4 v = ((const float4*)(C + (size_t)tok * EMB))[threadIdx.x];
  ushort4 o;
  o.x = f2b(v.x); o.y = f2b(v.y); o.z = f2b(v.z); o.w = f2b(v.w);
  ((ushort4*)(Xt + (size_t)n * EMB))[threadIdx.x] = o;
}

// ---------- fp32 -> bf16 bulk cast ----------
__global__ void castf_kernel(const float* __restrict__ src, unsigned short* __restrict__ dst,
                             int n4) {
  int i = blockIdx.x * blockDim.x + threadIdx.x;
  if (i < n4) {
    float4 v = ((const float4*)src)[i];
    ushort4 o;
    o.x = f2b(v.x); o.y = f2b(v.y); o.z = f2b(v.z); o.w = f2b(v.w);
    ((ushort4*)dst)[i] = o;
  }
}

// ---------- persistent fused bidirectional LSTM ----------
// 256 blocks (1/CU via 144 KB LDS), each owns (dir, batch-half 128, 16 units).
// Per step: gates = [x_t, h_{t-1}] @ W^T + bias. W_h (64x1024, 128 KB) resident in
// XOR-swizzled LDS all 256 steps; W_x double-buffer-streamed (16 KB); A-fragments
// per-lane direct from global (L2-hot). c in registers. h-phase has NO barriers.
// 4 independent 64-block flag-barrier groups, bailout-capped (cannot hang).
__launch_bounds__(256, 1)
__global__ void lstm_persist2(const unsigned short* __restrict__ Xt,
                              const unsigned short* __restrict__ Wcat,
                              const float* __restrict__ b0, const float* __restrict__ b1,
                              const float* __restrict__ b2, const float* __restrict__ b3,
                              const float* __restrict__ b4, const float* __restrict__ b5,
                              const float* __restrict__ b6, const float* __restrict__ b7,
                              unsigned short* __restrict__ hb0,
                              unsigned short* __restrict__ hb1,
                              unsigned int* __restrict__ flags) {
  __shared__ unsigned short Whlds[64 * 1024];   // 128 KB, rows of 2048 B, XOR-swizzled
  __shared__ unsigned short Bxs[2][4096];       // 2 x 8 KB, rows of 128 B, XOR-swizzled

  const int bid = blockIdx.x;
  const int dir = bid >> 7;
  const int mh  = (bid >> 6) & 1;
  const int ug  = bid & 63;
  const int j0  = ug * 16;
  const int tid = threadIdx.x;
  const int w   = tid >> 6;
  const int lane = tid & 63;
  const int lm = lane & 15, lq = lane >> 4;

  const unsigned short* Wd = Wcat + (size_t)dir * 4 * HID * KTOT;

  // ---- one-time W_h preload into swizzled LDS ----
  // physical byte P (linear in lane): row = P>>11; logical in-row = (P&2047)^((row&7)<<4)
#pragma unroll
  for (int i = 0; i < 32; ++i) {
    int P = (i * 256 + tid) << 4;
    int row = P >> 11;
    int offl = (P & 2047) ^ ((row & 7) << 4);
    int g = row >> 4, u = row & 15;
    load_lds16(Wd + (size_t)(g * HID + j0 + u) * KTOT + EMB + (offl >> 1),
               &Whlds[P >> 1]);
  }

  // ---- W_x staging: linear dest, inverse-swizzled source (2 slots/thread) ----
  const unsigned short* bxsrc[2];
  int bxdst[2];
#pragma unroll
  for (int r = 0; r < 2; ++r) {
    int P = (r * 256 + tid) << 4;     // 0..8191
    int row = P >> 7;                 // 0..63 (rows of 128 B; XOR bits 4-6 don't touch row)
    int L = P ^ ((row & 7) << 4);
    int g = row >> 4, u = row & 15;
    bxsrc[r] = Wd + (size_t)(g * HID + j0 + u) * KTOT + ((L & 127) >> 1);  // + ch*64
    bxdst[r] = P >> 1;
  }

  const int swz = (lm & 7) << 4;
  // A-fragment row offsets (elements); row stride 1024 for both Xt and h
  const int r0off = (w * 32 + lm) * 1024 + lq * 8;
  const int r1off = r0off + 16 * 1024;

  // ---- biases (folded once; reference inits them to ones but load anyway) ----
  const float* pbi = dir ? b4 : b0;
  const float* pbf = dir ? b5 : b1;
  const float* pbo = dir ? b6 : b2;
  const float* pbg = dir ? b7 : b3;
  const float vbi = pbi[j0 + lm], vbf = pbf[j0 + lm];
  const float vbo = pbo[j0 + lm], vbg = pbg[j0 + lm];

  f32x4 acc[2][4];
  float cs[2][4];
#pragma unroll
  for (int mi = 0; mi < 2; ++mi)
#pragma unroll
    for (int reg = 0; reg < 4; ++reg) cs[mi][reg] = 0.f;

  const size_t hblk = ((size_t)dir * BATCH + mh * 128) * HID;
  unsigned int* fgrp = flags + (bid & ~63);
  const int rbb = w * 32 + lq * 4;    // + mi*16 + reg = batch row within half

  // ---- x-phase: acc = x_td @ Wx^T. Bx dbuf-staged; A direct from global. ----
  auto xphase = [&](int td) {
    const unsigned short* xs = Xt + ((size_t)td * BATCH + mh * 128) * EMB;
#pragma unroll
    for (int mi = 0; mi < 2; ++mi)
#pragma unroll
      for (int g = 0; g < 4; ++g) acc[mi][g] = (f32x4){0.f, 0.f, 0.f, 0.f};
    load_lds16(bxsrc[0], &Bxs[0][bxdst[0]]);
    load_lds16(bxsrc[1], &Bxs[0][bxdst[1]]);
    bf16x8 xc00 = *(const bf16x8*)(xs + r0off);
    bf16x8 xc01 = *(const bf16x8*)(xs + r1off);
    bf16x8 xc10 = *(const bf16x8*)(xs + r0off + 32);
    bf16x8 xc11 = *(const bf16x8*)(xs + r1off + 32);
#pragma unroll
    for (int ch = 0; ch < 16; ++ch) {
      int cur = ch & 1;
      __syncthreads();                // Bxs[cur] + this chunk's A-regs drained/ready
      bf16x8 xn00 = xc00, xn01 = xc01, xn10 = xc10, xn11 = xc11;
      if (ch < 15) {
        load_lds16(bxsrc[0] + (ch + 1) * 64, &Bxs[1 - cur][bxdst[0]]);
        load_lds16(bxsrc[1] + (ch + 1) * 64, &Bxs[1 - cur][bxdst[1]]);
        int ko = (ch + 1) * 64;
        xn00 = *(const bf16x8*)(xs + r0off + ko);
        xn01 = *(const bf16x8*)(xs + r1off + ko);
        xn10 = *(const bf16x8*)(xs + r0off + ko + 32);
        xn11 = *(const bf16x8*)(xs + r1off + ko + 32);
      }
#pragma unroll
      for (int kc = 0; kc < 2; ++kc) {
        bf16x8 a0 = kc ? xc10 : xc00;
        bf16x8 a1 = kc ? xc11 : xc01;
#pragma unroll
        for (int g = 0; g < 4; ++g) {
          int offB = (((g * 16 + lm) * 128 + kc * 64 + lq * 16) ^ swz) >> 1;
          bf16x8 bb = *(const bf16x8*)&Bxs[cur][offB];
          acc[0][g] = __builtin_amdgcn_mfma_f32_16x16x32_bf16(a0, bb, acc[0][g], 0, 0, 0);
          acc[1][g] = __builtin_amdgcn_mfma_f32_16x16x32_bf16(a1, bb, acc[1][g], 0, 0, 0);
        }
      }
      xc00 = xn00; xc01 = xn01; xc10 = xn10; xc11 = xn11;
    }
  };

  // ---- h-phase: acc += h_{t-1} @ Wh^T. No barriers; A direct, Wh resident. ----
  auto hphase = [&](const unsigned short* hp) {
    bf16x8 ac0 = *(const bf16x8*)(hp + r0off);
    bf16x8 ac1 = *(const bf16x8*)(hp + r1off);
#pragma unroll
    for (int kb = 0; kb < 32; ++kb) {
      bf16x8 an0 = ac0, an1 = ac1;
      if (kb < 31) {
        an0 = *(const bf16x8*)(hp + r0off + (kb + 1) * 32);
        an1 = *(const bf16x8*)(hp + r1off + (kb + 1) * 32);
      }
      int offW = ((kb * 64 + lq * 16) ^ swz) >> 1;
#pragma unroll
      for (int g = 0; g < 4; ++g) {
        bf16x8 bb = *(const bf16x8*)&Whlds[(g * 16 + lm) * 1024 + offW];
        acc[0][g] = __builtin_amdgcn_mfma_f32_16x16x32_bf16(ac0, bb, acc[0][g], 0, 0, 0);
        acc[1][g] = __builtin_amdgcn_mfma_f32_16x16x32_bf16(ac1, bb, acc[1][g], 0, 0, 0);
      }
      ac0 = an0; ac1 = an1;
    }
  };

  // prologue: x-gates for t=0
  xphase(dir ? SEQ - 1 : 0);

  for (int t = 0; t < SEQ; ++t) {
    if (t > 0) hphase(((t & 1) ? hb1 : hb0) + hblk);
    unsigned short* hnext = ((t & 1) ? hb0 : hb1) + hblk;

    // ---- fused gate epilogue; c stays in registers ----
#pragma unroll
    for (int mi = 0; mi < 2; ++mi) {
#pragma unroll
      for (int reg = 0; reg < 4; ++reg) {
        float pi = acc[mi][0][reg] + vbi;
        float pf = acc[mi][1][reg] + vbf;
        float po = acc[mi][2][reg] + vbo;
        float pg = acc[mi][3][reg] + vbg;
        float ig = 1.f / (1.f + __expf(-pi));
        float fg = 1.f / (1.f + __expf(-pf));
        float og = 1.f / (1.f + __expf(-po));
        float gg = tanh_fast(pg);
        float cn = fg * cs[mi][reg] + ig * gg;
        cs[mi][reg] = cn;
        int rb = rbb + mi * 16 + reg;
        hnext[(size_t)rb * HID + j0 + lm] = f2b(og * tanh_fast(cn));
      }
    }

    if (t < SEQ - 1) {
      __syncthreads();                // all waves' h-stores drained (vmcnt 0)
      if (tid == 0) {
        __threadfence();              // release: write back L2 (cross-XCD)
        __hip_atomic_store(&flags[bid], (unsigned)(t + 1),
                           __ATOMIC_RELEASE, __HIP_MEMORY_SCOPE_AGENT);
      }
      // overlap barrier latency with next step's x-GEMM (independent of h)
      xphase(dir ? (SEQ - 2 - t) : (t + 1));
      if (tid < 64) {                 // wave 0: lane i polls group-block i's flag
        unsigned tgt = (unsigned)(t + 1);
        for (int spin = 0; spin < (1 << 16); ++spin) {   // bailout: cannot hang
          unsigned v = __hip_atomic_load(&fgrp[tid], __ATOMIC_ACQUIRE,
                                         __HIP_MEMORY_SCOPE_AGENT);
          if (__all((int)(v >= tgt))) break;
        }
      }
      __syncthreads();
      __threadfence();                // acquire: invalidate stale L1/L2 lines
    }
  }
}

// ---------- hsum = bf16(h1 + h2) ----------
__global__ void hsum_kernel(const unsigned short* __restrict__ hfin,
                            unsigned short* __restrict__ hs) {
  int i = blockIdx.x * 256 + threadIdx.x;
  ushort4 a = ((const ushort4*)hfin)[i];
  ushort4 b = ((const ushort4*)(hfin + (size_t)BATCH * HID))[i];
  ushort4 o;
  o.x = f2b(b2f(a.x) + b2f(b.x));
  o.y = f2b(b2f(a.y) + b2f(b.y));
  o.z = f2b(b2f(a.z) + b2f(b.z));
  o.w = f2b(b2f(a.w) + b2f(b.w));
  ((ushort4*)hs)[i] = o;
}

// ---------- output GEMM: out[b][n] = hsum[b] . Wout[n] + b_out[n] ----------
__launch_bounds__(256)
__global__ void out_gemm_kernel(const unsigned short* __restrict__ A,   // [256][1024]
                                const unsigned short* __restrict__ B,   // [32000][1024]
                                const float* __restrict__ bias,
                                float* __restrict__ Cout) {
  __shared__ unsigned short As[2][128][64];
  __shared__ unsigned short Bs[2][128][64];
  int bid = blockIdx.x;                 // 2 Mtiles x 250 Ntiles
  int m0 = (bid & 1) * 128;
  int n0 = (bid >> 1) * 128;
  int tid = threadIdx.x;

  auto stage = [&](int buf, int kb) {
    int kbase = kb * 64;
#pragma unroll
    for (int ri = 0; ri < 4; ++ri) {
      int slot = ri * 256 + tid;
      int row = slot >> 3;
      int ce  = (slot & 7) * 8;
      load_lds16(A + ((size_t)(m0 + row)) * HID + kbase + ce, &As[buf][row][ce]);
    }
#pragma unroll
    for (int ri = 0; ri < 4; ++ri) {
      int slot = ri * 256 + tid;
      int row = slot >> 3;
      int ce  = (slot & 7) * 8;
      load_lds16(B + ((size_t)(n0 + row)) * HID + kbase + ce, &Bs[buf][row][ce]);
    }
  };

  int w = tid >> 6, lane = tid & 63;
  int lm = lane & 15, lq = lane >> 4;
  int wm = w & 1, wn = w >> 1;

  f32x4 zero = {0.f, 0.f, 0.f, 0.f};
  f32x4 acc[4][4];
#pragma unroll
  for (int mi = 0; mi < 4; ++mi)
#pragma unroll
    for (int ni = 0; ni < 4; ++ni) acc[mi][ni] = zero;

  stage(0, 0);
  for (int kb = 0; kb < 16; ++kb) {
    int cur = kb & 1;
    __syncthreads();
    if (kb + 1 < 16) stage(1 - cur, kb + 1);
#pragma unroll
    for (int kc = 0; kc < 2; ++kc) {
      bf16x8 af[4];
#pragma unroll
      for (int mi = 0; mi < 4; ++mi)
        af[mi] = *(const bf16x8*)&As[cur][wm * 64 + mi * 16 + lm][kc * 32 + lq * 8];
#pragma unroll
      for (int ni = 0; ni < 4; ++ni) {
        bf16x8 bb = *(const bf16x8*)&Bs[cur][wn * 64 + ni * 16 + lm][kc * 32 + lq * 8];
#pragma unroll
        for (int mi = 0; mi < 4; ++mi)
          acc[mi][ni] = __builtin_amdgcn_mfma_f32_16x16x32_bf16(af[mi], bb, acc[mi][ni], 0, 0, 0);
      }
    }
  }

#pragma unroll
  for (int ni = 0; ni < 4; ++ni) {
    int n = n0 + wn * 64 + ni * 16 + lm;
    float bn = bias[n];
#pragma unroll
    for (int mi = 0; mi < 4; ++mi) {
#pragma unroll
      for (int reg = 0; reg < 4; ++reg) {
        int m = m0 + wm * 64 + mi * 16 + lq * 4 + reg;
        Cout[(size_t)m * NCLASS + n] = acc[mi][ni][reg] + bn;
      }
    }
  }
}

// ---------- host launcher ----------
extern "C" void kernel_launch(void* const* d_in, const int* in_sizes, int n_in,
                              void* d_out, int out_size, void* d_ws, size_t ws_size,
                              hipStream_t stream) {
  const int*   X    = (const int*)d_in[0];
  const float* C    = (const float*)d_in[1];
  const float* Wg[8];
  for (int i = 0; i < 8; ++i) Wg[i] = (const float*)d_in[2 + i];
  const float* bg[8];
  for (int i = 0; i < 8; ++i) bg[i] = (const float*)d_in[10 + i];
  const float* Wout = (const float*)d_in[18];
  const float* bout = (const float*)d_in[19];
  float* out = (float*)d_out;

  // workspace carve (~236 MB total -- no Gx buffer)
  const size_t szXt   = (size_t)SEQ * BATCH * EMB * 2;      // 134.2 MB
  const size_t szWcat = (size_t)8 * HID * KTOT * 2;         //  33.6 MB
  const size_t szWob  = (size_t)NCLASS * HID * 2;           //  65.5 MB
  const size_t szH    = (size_t)2 * BATCH * HID * 2;        //   1  MB
  const size_t szFl   = 4096;                               // flag barrier
  const size_t szHs   = (size_t)BATCH * HID * 2;            // 0.5 MB

  uint8_t* p = (uint8_t*)d_ws;
  unsigned short* Xt   = (unsigned short*)p; p += szXt;
  unsigned short* Wcat = (unsigned short*)p; p += szWcat;
  unsigned short* Wob  = (unsigned short*)p; p += szWob;
  unsigned short* hb0  = (unsigned short*)p; p += szH;
  unsigned short* hb1  = (unsigned short*)p; p += szH;
  unsigned int*   flags= (unsigned int*)p;   p += szFl;
  unsigned short* hs   = (unsigned short*)p; p += szHs;

  hipMemsetAsync(flags, 0, szFl, stream);   // barrier flags (per-launch, replay-safe)

  embed_kernel<<<SEQ * BATCH, 256, 0, stream>>>(X, C, Xt);
  for (int i = 0; i < 8; ++i)
    castf_kernel<<<2048, 256, 0, stream>>>(Wg[i], Wcat + (size_t)i * HID * KTOT,
                                           (HID * KTOT) / 4);
  castf_kernel<<<32000, 256, 0, stream>>>(Wout, Wob, (NCLASS * HID) / 4);

  // persistent fused recurrence: one launch, both dirs, all 256 steps
  lstm_persist2<<<256, 256, 0, stream>>>(
      Xt, Wcat,
      bg[0], bg[1], bg[2], bg[3], bg[4], bg[5], bg[6], bg[7],
      hb0, hb1, flags);

  // final h is in hb0 after 256 steps (t=255 writes hb0)
  hsum_kernel<<<256, 256, 0, stream>>>(hb0, hs);
  out_gemm_kernel<<<500, 256, 0, stream>>>(hs, Wob, bout, out);
}

// Round 4
// 8947.662 us; speedup vs baseline: 1.5955x; 1.5955x over previous
//
#include <hip/hip_runtime.h>
#include <hip/hip_bf16.h>
#include <stdint.h>
#include <math.h>

#define BATCH 256
#define SEQ   256
#define EMB   1024
#define HID   1024
#define NCLASS 32000
#define KTOT  2048   // EMB + HID

typedef __attribute__((ext_vector_type(8))) short bf16x8;   // 8 bf16 (4 VGPRs)
typedef __attribute__((ext_vector_type(4))) float f32x4;    // MFMA accumulator

// ---------- scalar helpers ----------
__device__ __forceinline__ unsigned short f2b(float f) {
  union { float f; unsigned u; } v; v.f = f;
  unsigned r = v.u + 0x7FFFu + ((v.u >> 16) & 1u);   // round-to-nearest-even
  return (unsigned short)(r >> 16);
}
__device__ __forceinline__ float b2f(unsigned short s) {
  union { unsigned u; float f; } v; v.u = ((unsigned)s) << 16;
  return v.f;
}
__device__ __forceinline__ void load_lds16(const void* g, void* l) {
  __builtin_amdgcn_global_load_lds(
      (const __attribute__((address_space(1))) unsigned int*)g,
      (__attribute__((address_space(3))) unsigned int*)l, 16, 0, 0);
}
__device__ __forceinline__ float tanh_fast(float x) {
  // 1 - 2/(e^{2x}+1): saturates to +-1, no NaN at large |x|
  return 1.f - 2.f / (__expf(2.f * x) + 1.f);
}

// ---------- embedding lookup + bf16 cast:  Xt[t*B+b][k] = bf16(C[X[b][t]][k]) ----------
__global__ void embed_kernel(const int* __restrict__ X, const float* __restrict__ C,
                             unsigned short* __restrict__ Xt) {
  int n = blockIdx.x;             // n = t*BATCH + b
  int t = n >> 8, b = n & 255;
  int tok = X[(size_t)b * SEQ + t];
  float4 v = ((const float4*)(C + (size_t)tok * EMB))[threadIdx.x];
  ushort4 o;
  o.x = f2b(v.x); o.y = f2b(v.y); o.z = f2b(v.z); o.w = f2b(v.w);
  ((ushort4*)(Xt + (size_t)n * EMB))[threadIdx.x] = o;
}

// ---------- fp32 -> bf16 bulk cast ----------
__global__ void castf_kernel(const float* __restrict__ src, unsigned short* __restrict__ dst,
                             int n4) {
  int i = blockIdx.x * blockDim.x + threadIdx.x;
  if (i < n4) {
    float4 v = ((const float4*)src)[i];
    ushort4 o;
    o.x = f2b(v.x); o.y = f2b(v.y); o.z = f2b(v.z); o.w = f2b(v.w);
    ((ushort4*)dst)[i] = o;
  }
}

// ---------- persistent fused bidirectional LSTM (v3) ----------
// 256 blocks x 512 threads (8 waves, 1 block/CU via 160 KB LDS).
// Block owns (dir, batch-half 128, 16 units); group = bid&3 -> group's 64 blocks
// land on an XCD pair under round-robin dispatch (locality only, not correctness).
// W_h resident in swizzled LDS (128 KB) all 256 steps; W_x double-buffered BK=128
// (2x16 KB, issue-after-barrier); A-fragments per-lane from global.
// h_{t-1} is read via RELAXED AGENT-SCOPE ATOMIC loads (coherent at L3, bypass
// stale L1/L2) -> NO acquire fence -> W_x/Xt stay L2-resident across steps.
// c-state in registers. Flag barrier per group, bailout-capped.
__launch_bounds__(512, 1)
__global__ void lstm_persist3(const unsigned short* __restrict__ Xt,
                              const unsigned short* __restrict__ Wcat,
                              const float* __restrict__ b0, const float* __restrict__ b1,
                              const float* __restrict__ b2, const float* __restrict__ b3,
                              const float* __restrict__ b4, const float* __restrict__ b5,
                              const float* __restrict__ b6, const float* __restrict__ b7,
                              unsigned short* __restrict__ hb0,
                              unsigned short* __restrict__ hb1,
                              unsigned int* __restrict__ flags) {
  __shared__ unsigned short Whlds[64 * 1024];   // 128 KB, rows 2048 B, XOR-swizzled
  __shared__ unsigned short Bxs[2][8192];       // 2 x 16 KB, rows 256 B, XOR-swizzled

  const int bid = blockIdx.x;
  const int grp = bid & 3;            // group: same (dir, mh) -> XCD pair {g, g+4}
  const int ug  = bid >> 2;           // 0..63 unit-group
  const int dir = grp >> 1;
  const int mh  = grp & 1;
  const int j0  = ug * 16;
  const int tid = threadIdx.x;
  const int w   = tid >> 6;           // 8 waves
  const int lane = tid & 63;
  const int lm = lane & 15, lq = lane >> 4;

  const unsigned short* Wd = Wcat + (size_t)dir * 4 * HID * KTOT;

  // ---- one-time W_h preload into swizzled LDS ----
  // rows of 2048 B; physical P: row = P>>11; logical in-row = (P&2047)^((row&7)<<4)
#pragma unroll
  for (int i = 0; i < 16; ++i) {
    int P = (i * 512 + tid) << 4;
    int row = P >> 11;
    int offl = (P & 2047) ^ ((row & 7) << 4);
    int g = row >> 4, u = row & 15;
    load_lds16(Wd + (size_t)(g * HID + j0 + u) * KTOT + EMB + (offl >> 1),
               &Whlds[P >> 1]);
  }

  // ---- W_x staging slots: linear LDS dest, inverse-swizzled global source ----
  // Bxs rows of 256 B (chunk BK=128 elems); row = P>>8; XOR bits 4-6 only.
  const unsigned short* bxsrc[2];
  int bxdst[2];
#pragma unroll
  for (int r = 0; r < 2; ++r) {
    int P = (r * 512 + tid) << 4;     // 0..16383
    int row = P >> 8;                 // 0..63 (= g*16 + u)
    int L = P ^ ((row & 7) << 4);
    int g = row >> 4, u = row & 15;
    bxsrc[r] = Wd + (size_t)(g * HID + j0 + u) * KTOT + ((L & 255) >> 1);  // + ch*128
    bxdst[r] = P >> 1;
  }

  const int swz = (lm & 7) << 4;
  const int abase = (w * 16 + lm) * 1024 + lq * 8;   // A-fragment element offset

  // ---- biases (folded once) ----
  const float* pbi = dir ? b4 : b0;
  const float* pbf = dir ? b5 : b1;
  const float* pbo = dir ? b6 : b2;
  const float* pbg = dir ? b7 : b3;
  const float vbi = pbi[j0 + lm], vbf = pbf[j0 + lm];
  const float vbo = pbo[j0 + lm], vbg = pbg[j0 + lm];

  f32x4 acc[4];
  float cs[4];
#pragma unroll
  for (int r = 0; r < 4; ++r) cs[r] = 0.f;

  const size_t hblk = ((size_t)dir * BATCH + mh * 128) * HID;
  const int rbb = w * 16 + lq * 4;    // + reg = batch row within half

  // ---- x-phase: acc = x_td @ Wx^T. BK=128, dbuf, issue-after-barrier. ----
  auto xphase = [&](int td) {
    const unsigned short* xs = Xt + ((size_t)td * BATCH + mh * 128) * EMB;
#pragma unroll
    for (int g = 0; g < 4; ++g) acc[g] = (f32x4){0.f, 0.f, 0.f, 0.f};
    load_lds16(bxsrc[0], &Bxs[0][bxdst[0]]);
    load_lds16(bxsrc[1], &Bxs[0][bxdst[1]]);
    bf16x8 ax[2][4];
#pragma unroll
    for (int kc = 0; kc < 4; ++kc)
      ax[0][kc] = *(const bf16x8*)(xs + abase + kc * 32);
#pragma unroll
    for (int ch = 0; ch < 8; ++ch) {
      int cur = ch & 1;
      __syncthreads();                 // Bxs[cur] DMA drained (issued 1 chunk ago)
      if (ch < 7) {                    // issue-after-barrier: covered by compute
        load_lds16(bxsrc[0] + (ch + 1) * 128, &Bxs[1 - cur][bxdst[0]]);
        load_lds16(bxsrc[1] + (ch + 1) * 128, &Bxs[1 - cur][bxdst[1]]);
#pragma unroll
        for (int kc = 0; kc < 4; ++kc)
          ax[1 - cur][kc] = *(const bf16x8*)(xs + abase + (ch + 1) * 128 + kc * 32);
      }
#pragma unroll
      for (int kc = 0; kc < 4; ++kc) {
#pragma unroll
        for (int g = 0; g < 4; ++g) {
          int offB = ((g * 16 + lm) * 256 + ((kc * 64 + lq * 16) ^ swz)) >> 1;
          bf16x8 bb = *(const bf16x8*)&Bxs[cur][offB];
          acc[g] = __builtin_amdgcn_mfma_f32_16x16x32_bf16(ax[cur][kc], bb, acc[g], 0, 0, 0);
        }
      }
    }
  };

  // ---- h-phase: acc += h_{t-1} @ Wh^T. Atomic A-loads (L3-coherent), no barrier,
  //      6-deep prefetch in a rotating 8-slot register file (static indices). ----
  auto hphase = [&](const unsigned short* hp) {
    unsigned long long qa[8][2];
#pragma unroll
    for (int p = 0; p < 6; ++p) {
      unsigned long long* s = (unsigned long long*)(hp + abase + p * 32);
      qa[p][0] = __hip_atomic_load(s,     __ATOMIC_RELAXED, __HIP_MEMORY_SCOPE_AGENT);
      qa[p][1] = __hip_atomic_load(s + 1, __ATOMIC_RELAXED, __HIP_MEMORY_SCOPE_AGENT);
    }
#pragma unroll
    for (int kb = 0; kb < 32; ++kb) {
      if (kb + 6 < 32) {
        unsigned long long* s = (unsigned long long*)(hp + abase + (kb + 6) * 32);
        qa[(kb + 6) & 7][0] = __hip_atomic_load(s,     __ATOMIC_RELAXED, __HIP_MEMORY_SCOPE_AGENT);
        qa[(kb + 6) & 7][1] = __hip_atomic_load(s + 1, __ATOMIC_RELAXED, __HIP_MEMORY_SCOPE_AGENT);
      }
      union { unsigned long long q[2]; bf16x8 v; } u;
      u.q[0] = qa[kb & 7][0];
      u.q[1] = qa[kb & 7][1];
      int offW = ((kb * 64 + lq * 16) ^ swz) >> 1;
#pragma unroll
      for (int g = 0; g < 4; ++g) {
        bf16x8 bb = *(const bf16x8*)&Whlds[(g * 16 + lm) * 1024 + offW];
        acc[g] = __builtin_amdgcn_mfma_f32_16x16x32_bf16(u.v, bb, acc[g], 0, 0, 0);
      }
    }
  };

  // prologue: x-gates for t=0
  xphase(dir ? SEQ - 1 : 0);

  for (int t = 0; t < SEQ; ++t) {
    if (t > 0) hphase((((t & 1) ? hb1 : hb0) + hblk));
    unsigned short* hnext = ((t & 1) ? hb0 : hb1) + hblk;

    // ---- fused gate epilogue; c stays in registers ----
#pragma unroll
    for (int reg = 0; reg < 4; ++reg) {
      float pi = acc[0][reg] + vbi;
      float pf = acc[1][reg] + vbf;
      float po = acc[2][reg] + vbo;
      float pg = acc[3][reg] + vbg;
      float ig = 1.f / (1.f + __expf(-pi));
      float fg = 1.f / (1.f + __expf(-pf));
      float og = 1.f / (1.f + __expf(-po));
      float gg = tanh_fast(pg);
      float cn = fg * cs[reg] + ig * gg;
      cs[reg] = cn;
      hnext[(size_t)(rbb + reg) * HID + j0 + lm] = f2b(og * tanh_fast(cn));
    }

    if (t < SEQ - 1) {
      __syncthreads();                 // all waves' h-stores at L2 (vmcnt drained)
      if (tid == 0) {
        __threadfence();               // release: writeback L2 -> L3 (no invalidate)
        __hip_atomic_store(&flags[bid], (unsigned)(t + 1),
                           __ATOMIC_RELAXED, __HIP_MEMORY_SCOPE_AGENT);
      }
      // overlap flag propagation + peers' tails with next step's x-GEMM
      xphase(dir ? (SEQ - 2 - t) : (t + 1));
      if (tid < 64) {                  // lane i polls peer block i of this group
        unsigned tgt = (unsigned)(t + 1);
        unsigned int* fp = &flags[tid * 4 + grp];
        for (int spin = 0; spin < (1 << 15); ++spin) {
          unsigned v = __hip_atomic_load(fp, __ATOMIC_RELAXED,
                                         __HIP_MEMORY_SCOPE_AGENT);
          if (__all((int)(v >= tgt))) break;
        }
      }
      __syncthreads();
      __builtin_amdgcn_sched_barrier(0);   // keep h atomic-loads below the poll
    }
  }
}

// ---------- hsum = bf16(h1 + h2) ----------
__global__ void hsum_kernel(const unsigned short* __restrict__ hfin,
                            unsigned short* __restrict__ hs) {
  int i = blockIdx.x * 256 + threadIdx.x;
  ushort4 a = ((const ushort4*)hfin)[i];
  ushort4 b = ((const ushort4*)(hfin + (size_t)BATCH * HID))[i];
  ushort4 o;
  o.x = f2b(b2f(a.x) + b2f(b.x));
  o.y = f2b(b2f(a.y) + b2f(b.y));
  o.z = f2b(b2f(a.z) + b2f(b.z));
  o.w = f2b(b2f(a.w) + b2f(b.w));
  ((ushort4*)hs)[i] = o;
}

// ---------- output GEMM: out[b][n] = hsum[b] . Wout[n] + b_out[n] ----------
__launch_bounds__(256)
__global__ void out_gemm_kernel(const unsigned short* __restrict__ A,   // [256][1024]
                                const unsigned short* __restrict__ B,   // [32000][1024]
                                const float* __restrict__ bias,
                                float* __restrict__ Cout) {
  __shared__ unsigned short As[2][128][64];
  __shared__ unsigned short Bs[2][128][64];
  int bid = blockIdx.x;                 // 2 Mtiles x 250 Ntiles
  int m0 = (bid & 1) * 128;
  int n0 = (bid >> 1) * 128;
  int tid = threadIdx.x;

  auto stage = [&](int buf, int kb) {
    int kbase = kb * 64;
#pragma unroll
    for (int ri = 0; ri < 4; ++ri) {
      int slot = ri * 256 + tid;
      int row = slot >> 3;
      int ce  = (slot & 7) * 8;
      load_lds16(A + ((size_t)(m0 + row)) * HID + kbase + ce, &As[buf][row][ce]);
    }
#pragma unroll
    for (int ri = 0; ri < 4; ++ri) {
      int slot = ri * 256 + tid;
      int row = slot >> 3;
      int ce  = (slot & 7) * 8;
      load_lds16(B + ((size_t)(n0 + row)) * HID + kbase + ce, &Bs[buf][row][ce]);
    }
  };

  int w = tid >> 6, lane = tid & 63;
  int lm = lane & 15, lq = lane >> 4;
  int wm = w & 1, wn = w >> 1;

  f32x4 zero = {0.f, 0.f, 0.f, 0.f};
  f32x4 acc[4][4];
#pragma unroll
  for (int mi = 0; mi < 4; ++mi)
#pragma unroll
    for (int ni = 0; ni < 4; ++ni) acc[mi][ni] = zero;

  stage(0, 0);
  for (int kb = 0; kb < 16; ++kb) {
    int cur = kb & 1;
    __syncthreads();
    if (kb + 1 < 16) stage(1 - cur, kb + 1);
#pragma unroll
    for (int kc = 0; kc < 2; ++kc) {
      bf16x8 af[4];
#pragma unroll
      for (int mi = 0; mi < 4; ++mi)
        af[mi] = *(const bf16x8*)&As[cur][wm * 64 + mi * 16 + lm][kc * 32 + lq * 8];
#pragma unroll
      for (int ni = 0; ni < 4; ++ni) {
        bf16x8 bb = *(const bf16x8*)&Bs[cur][wn * 64 + ni * 16 + lm][kc * 32 + lq * 8];
#pragma unroll
        for (int mi = 0; mi < 4; ++mi)
          acc[mi][ni] = __builtin_amdgcn_mfma_f32_16x16x32_bf16(af[mi], bb, acc[mi][ni], 0, 0, 0);
      }
    }
  }

#pragma unroll
  for (int ni = 0; ni < 4; ++ni) {
    int n = n0 + wn * 64 + ni * 16 + lm;
    float bn = bias[n];
#pragma unroll
    for (int mi = 0; mi < 4; ++mi) {
#pragma unroll
      for (int reg = 0; reg < 4; ++reg) {
        int m = m0 + wm * 64 + mi * 16 + lq * 4 + reg;
        Cout[(size_t)m * NCLASS + n] = acc[mi][ni][reg] + bn;
      }
    }
  }
}

// ---------- host launcher ----------
extern "C" void kernel_launch(void* const* d_in, const int* in_sizes, int n_in,
                              void* d_out, int out_size, void* d_ws, size_t ws_size,
                              hipStream_t stream) {
  const int*   X    = (const int*)d_in[0];
  const float* C    = (const float*)d_in[1];
  const float* Wg[8];
  for (int i = 0; i < 8; ++i) Wg[i] = (const float*)d_in[2 + i];
  const float* bg[8];
  for (int i = 0; i < 8; ++i) bg[i] = (const float*)d_in[10 + i];
  const float* Wout = (const float*)d_in[18];
  const float* bout = (const float*)d_in[19];
  float* out = (float*)d_out;

  // workspace carve (~236 MB)
  const size_t szXt   = (size_t)SEQ * BATCH * EMB * 2;      // 134.2 MB
  const size_t szWcat = (size_t)8 * HID * KTOT * 2;         //  33.6 MB
  const size_t szWob  = (size_t)NCLASS * HID * 2;           //  65.5 MB
  const size_t szH    = (size_t)2 * BATCH * HID * 2;        //   1  MB
  const size_t szFl   = 4096;                               // flag barrier
  const size_t szHs   = (size_t)BATCH * HID * 2;            // 0.5 MB

  uint8_t* p = (uint8_t*)d_ws;
  unsigned short* Xt   = (unsigned short*)p; p += szXt;
  unsigned short* Wcat = (unsigned short*)p; p += szWcat;
  unsigned short* Wob  = (unsigned short*)p; p += szWob;
  unsigned short* hb0  = (unsigned short*)p; p += szH;
  unsigned short* hb1  = (unsigned short*)p; p += szH;
  unsigned int*   flags= (unsigned int*)p;   p += szFl;
  unsigned short* hs   = (unsigned short*)p; p += szHs;

  hipMemsetAsync(flags, 0, szFl, stream);   // barrier flags (per-launch, replay-safe)

  embed_kernel<<<SEQ * BATCH, 256, 0, stream>>>(X, C, Xt);
  for (int i = 0; i < 8; ++i)
    castf_kernel<<<2048, 256, 0, stream>>>(Wg[i], Wcat + (size_t)i * HID * KTOT,
                                           (HID * KTOT) / 4);
  castf_kernel<<<32000, 256, 0, stream>>>(Wout, Wob, (NCLASS * HID) / 4);

  // persistent fused recurrence: one launch, both dirs, all 256 steps
  lstm_persist3<<<256, 512, 0, stream>>>(
      Xt, Wcat,
      bg[0], bg[1], bg[2], bg[3], bg[4], bg[5], bg[6], bg[7],
      hb0, hb1, flags);

  // final h is in hb0 after 256 steps (t=255 writes hb0)
  hsum_kernel<<<256, 256, 0, stream>>>(hb0, hs);
  out_gemm_kernel<<<500, 256, 0, stream>>>(hs, Wob, bout, out);
}